// Round 6
// baseline (147.052 us; speedup 1.0000x reference)
//
#include <hip/hip_runtime.h>
#include <hip/hip_bf16.h>

// ===================================================================================
// Verified lineage (R6-R11, absmax 3.05e-5): argmin bit-replicates numpy-f32:
//   zp  = einsum SSE mod-4 accumulators, reduce (l0+l1)+(l2+l3), + bq
//   A,B = pairwise f32 row-sum-of-squares (AVX512 npyv tree for n=64)
//   d   = fl32( fl32(A + B_k) - fl32(2*M_k) ), first-index ties
// R18 (this round): low-risk tightening on the R17 baseline (138.0us best).
//   - k_out_v2: 8 -> 32 tokens/block (grid T/32=256). The 64KB Wp->VGPR prologue
//     was repeated 1024x (64MB L2 re-reads + 1024 latency-chained prologues);
//     now amortized 4x. Loss fold stays in block 0 (no atomics/fences - R16 lesson).
//   - scan: pslice_t stores moved to half==1 lanes (macc identical in both halves
//     post-shfl) so they issue parallel to half 0's pmax32 stores. Free.
//   All argmin-relevant math byte-identical to R17. Replay-poison guards kept.
//   Launch chain: prep -> scan -> refine -> out  (4 launches).
// ===================================================================================

#define VWIN 1.0e-5f
#define CMAX 16

typedef short short8v __attribute__((ext_vector_type(8)));
typedef float floatx16 __attribute__((ext_vector_type(16)));

#ifndef __has_builtin
#define __has_builtin(x) 0
#endif
#if __has_builtin(__builtin_amdgcn_global_load_lds)
#define HAVE_GLL 1
#else
#define HAVE_GLL 0
#endif

// per-lane global src (already includes lane offset); wave-uniform LDS base.
__device__ __forceinline__ void stage16(const void* g, void* l, int lane) {
#if HAVE_GLL
    (void)lane;
    __builtin_amdgcn_global_load_lds(
        (const __attribute__((address_space(1))) void*)g,
        (__attribute__((address_space(3))) void*)l, 16, 0, 0);
#else
    ((float4*)l)[lane] = *(const float4*)g;
#endif
}
__device__ __forceinline__ void stage4(const void* g, void* l, int lane) {
#if HAVE_GLL
    (void)lane;
    __builtin_amdgcn_global_load_lds(
        (const __attribute__((address_space(1))) void*)g,
        (__attribute__((address_space(3))) void*)l, 4, 0, 0);
#else
    ((float*)l)[lane] = *(const float*)g;
#endif
}

__device__ __forceinline__ short f2bf(float x) {           // RTNE f32->bf16
    unsigned u = __builtin_bit_cast(unsigned, x);
    unsigned r = (u + 0x7fffu + ((u >> 16) & 1u)) >> 16;
    return (short)r;
}

__device__ __forceinline__ float np_pairwise64_sq(const float* __restrict__ p) {
    #pragma clang fp contract(off)
    float v[16];
#pragma unroll
    for (int j = 0; j < 16; ++j) {
        float x0 = p[j]      * p[j];
        float x1 = p[j + 32] * p[j + 32];
        float x2 = p[j + 16] * p[j + 16];
        float x3 = p[j + 48] * p[j + 48];
        float r0 = x0 + x1;
        float r1 = x2 + x3;
        v[j] = r0 + r1;
    }
    float s[8], t[4];
#pragma unroll
    for (int j = 0; j < 8; ++j) s[j] = v[j] + v[j + 8];
#pragma unroll
    for (int j = 0; j < 4; ++j) t[j] = s[j] + s[j + 4];
    return (t[0] + t[2]) + (t[1] + t[3]);
}

// ---------------- merged prep: tok blocks (bx < tokblocks) + code blocks ------------
// tok: CD=64, DIN=256, 32 tokens/block, 512 threads -> zp32 + A32 + zpf.
// code: 2 tiles (64 codes)/block, 256 threads each half -> B32 + ef + bfl + embT4.
__global__ __launch_bounds__(512) void k_prep(const float* __restrict__ z,
                                              const float* __restrict__ Wq,
                                              const float* __restrict__ bq,
                                              const float* __restrict__ emb,
                                              float* __restrict__ zp32,
                                              float* __restrict__ A32,
                                              short8v* __restrict__ zpf,
                                              float* __restrict__ B32,
                                              short8v* __restrict__ ef,
                                              float* __restrict__ bfl,
                                              float4* __restrict__ embT4,
                                              int tokblocks, int K) {
    __shared__ float pool[64 * 129 + 32 * 128 + 32 * 65];   // 57.7 KB
    const int tid = threadIdx.x;
    const int bx  = blockIdx.x;

    if (bx < tokblocks) {
        float* wq  = pool;                       // 64*129
        float* zl  = pool + 64 * 129;            // 32*128
        float* zps = zl + 32 * 128;              // 32*65
        const int w    = tid >> 6;
        const int lane = tid & 63;
        const int tbase = bx * 32;

        float l[4][4];
#pragma unroll
        for (int i = 0; i < 4; ++i)
#pragma unroll
            for (int j = 0; j < 4; ++j) l[i][j] = 0.f;

        for (int h = 0; h < 2; ++h) {
            __syncthreads();
            for (int i = tid; i < 64 * 128; i += 512) {
                const int c = i >> 7, m = i & 127;
                wq[c * 129 + m] = Wq[(size_t)c * 256 + h * 128 + m];
            }
            // z tile: 32x128 f32 = 1024 float4; dest linear -> global_load_lds.
            for (int b4 = w * 64; b4 < 1024; b4 += 512) {
                const int i4 = b4 + lane;
                const int t  = i4 >> 5, m4 = i4 & 31;
                stage16(z + (size_t)(tbase + t) * 256 + h * 128 + m4 * 4,
                        zl + (size_t)b4 * 4, lane);
            }
            __syncthreads();
            {
                #pragma clang fp contract(off)
                const float* wr  = wq + lane * 129;
                const float* zt0 = zl + (w * 4 + 0) * 128;
                const float* zt1 = zl + (w * 4 + 1) * 128;
                const float* zt2 = zl + (w * 4 + 2) * 128;
                const float* zt3 = zl + (w * 4 + 3) * 128;
                for (int m = 0; m < 128; m += 4) {
                    const float w0 = wr[m], w1 = wr[m + 1], w2 = wr[m + 2], w3 = wr[m + 3];
                    const float4 p0 = *(const float4*)(zt0 + m);
                    const float4 p1 = *(const float4*)(zt1 + m);
                    const float4 p2 = *(const float4*)(zt2 + m);
                    const float4 p3 = *(const float4*)(zt3 + m);
                    l[0][0] += p0.x * w0; l[0][1] += p0.y * w1; l[0][2] += p0.z * w2; l[0][3] += p0.w * w3;
                    l[1][0] += p1.x * w0; l[1][1] += p1.y * w1; l[1][2] += p1.z * w2; l[1][3] += p1.w * w3;
                    l[2][0] += p2.x * w0; l[2][1] += p2.y * w1; l[2][2] += p2.z * w2; l[2][3] += p2.w * w3;
                    l[3][0] += p3.x * w0; l[3][1] += p3.y * w1; l[3][2] += p3.z * w2; l[3][3] += p3.w * w3;
                }
            }
        }
        {
            #pragma clang fp contract(off)
            const float bqc = bq[lane];
#pragma unroll
            for (int tk = 0; tk < 4; ++tk) {
                const float acc = (l[tk][0] + l[tk][1]) + (l[tk][2] + l[tk][3]);
                const float zpv = acc + bqc;
                zp32[(size_t)(tbase + w * 4 + tk) * 64 + lane] = zpv;
                zps[(w * 4 + tk) * 65 + lane] = zpv;
            }
        }
        __syncthreads();
        if (tid < 32) A32[tbase + tid] = np_pairwise64_sq(zps + tid * 65);
        if (tid < 256) {
            const int fl = tid & 63;
            const int s  = tid >> 6;
            const int row = fl & 31;
            const int k0 = s * 16 + (fl >> 5) * 8;
            short8v hv;
            const float* p = zps + row * 65 + k0;
#pragma unroll
            for (int j = 0; j < 8; ++j) hv[j] = f2bf(p[j]);
            zpf[(size_t)(bx * 4 + s) * 64 + fl] = hv;
        }
    } else {
        const int half = tid >> 8;                    // 0/1: which tile this half handles
        const int ltid = tid & 255;
        const int tile = (bx - tokblocks) * 2 + half;
        float* et = pool + half * (32 * 65);

        for (int i = ltid; i < 2048; i += 256)
            et[(i >> 6) * 65 + (i & 63)] = emb[(size_t)tile * 2048 + i];
        __syncthreads();
        if (ltid < 32) {
            const float b = np_pairwise64_sq(et + ltid * 65);
            B32[tile * 32 + ltid] = b;
            // f32 image of bf16(-B/2): bit-identical to mfma(bfrag, ones, 0) init.
            const unsigned hb = (unsigned)(unsigned short)f2bf(-0.5f * b);
            bfl[tile * 32 + ltid] = __builtin_bit_cast(float, hb << 16);
        }
        {
            const int fl = ltid & 63;
            const int s  = ltid >> 6;
            const int row = fl & 31;
            const int k0 = s * 16 + (fl >> 5) * 8;
            short8v hv;
            const float* p = et + row * 65 + k0;
#pragma unroll
            for (int j = 0; j < 8; ++j) hv[j] = f2bf(p[j]);
            ef[(size_t)(tile * 4 + s) * 64 + fl] = hv;
        }
        // exact f32 transpose: embT4[m4][j] = emb[j][4*m4 .. 4*m4+3]
#pragma unroll
        for (int p = 0; p < 2; ++p) {
            const int id = ltid + (p << 8);
            const int m4 = id >> 5;                   // 0..15
            const int r  = id & 31;
            const float* q = et + r * 65 + m4 * 4;
            float4 v;
            v.x = q[0]; v.y = q[1]; v.z = q[2]; v.w = q[3];
            embT4[(size_t)m4 * K + tile * 32 + r] = v;
        }
    }
}

// ---------------- pass-1: per-(token, ctile) MAX of v = M - B/2 ---------------------
// grid (T/512, 64); block stages its etiles-ctile slice via global_load_lds.
// Bias enters as MFMA C-operand (4 broadcast b128 reads). pmax32[ct][tok] coalesced
// (half 0 lanes); pslice_t[tok][64] per-slice max (half 1 lanes, parallel stores).
__global__ __launch_bounds__(256) void k_scan_max(const short8v* __restrict__ zpf,
                                                  const short8v* __restrict__ ef,
                                                  const float* __restrict__ bfl,
                                                  float* __restrict__ pmax32,
                                                  float* __restrict__ pslice_t,
                                                  int tokens, int K) {
    __shared__ __align__(16) short8v s_ef[2048];   // up to 8 ctiles x 4 x 64 (32 KB)
    __shared__ __align__(16) float s_bfl[256];     // up to 8 ctiles x 32 rows (1 KB)
    const int tid  = threadIdx.x;
    const int w    = tid >> 6;
    const int lane = tid & 63;
    const int half = lane >> 5;
    const int col  = lane & 31;
    const int ttb  = (blockIdx.x * 4 + w) * 4;
    const int etiles = K / 2048;                  // 8 for K=16384
    const int ct0 = blockIdx.y * etiles;

    for (int base = w * 64; base < etiles * 256; base += 256)
        stage16(&ef[(size_t)ct0 * 256 + base + lane], &s_ef[base], lane);
    {
        const int base = w * 64;
        if (base + lane < etiles * 32)
            stage4(&bfl[(size_t)ct0 * 32 + base + lane], &s_bfl[base], lane);
    }

    short8v zh[4][4];
#pragma unroll
    for (int q = 0; q < 4; ++q)
#pragma unroll
        for (int s = 0; s < 4; ++s) zh[q][s] = zpf[(size_t)((ttb + q) * 4 + s) * 64 + lane];

    __syncthreads();

    float macc[4] = {-3.0e38f, -3.0e38f, -3.0e38f, -3.0e38f};

    for (int it = 0; it < etiles; ++it) {
        short8v eh[4];
#pragma unroll
        for (int s = 0; s < 4; ++s) eh[s] = s_ef[it * 256 + s * 64 + lane];
        // binit[r] = s_bfl[it*32 + (r&3) + 8*(r>>2) + 4*half]; 4 broadcast b128 reads.
        const float4 b0 = *(const float4*)(s_bfl + it * 32 +  0 + 4 * half);
        const float4 b1 = *(const float4*)(s_bfl + it * 32 +  8 + 4 * half);
        const float4 b2 = *(const float4*)(s_bfl + it * 32 + 16 + 4 * half);
        const float4 b3 = *(const float4*)(s_bfl + it * 32 + 24 + 4 * half);
        floatx16 binit;
        binit[0]  = b0.x; binit[1]  = b0.y; binit[2]  = b0.z; binit[3]  = b0.w;
        binit[4]  = b1.x; binit[5]  = b1.y; binit[6]  = b1.z; binit[7]  = b1.w;
        binit[8]  = b2.x; binit[9]  = b2.y; binit[10] = b2.z; binit[11] = b2.w;
        binit[12] = b3.x; binit[13] = b3.y; binit[14] = b3.z; binit[15] = b3.w;
#pragma unroll
        for (int q = 0; q < 4; ++q) {
            floatx16 acc = __builtin_amdgcn_mfma_f32_32x32x16_bf16(eh[0], zh[q][0], binit, 0, 0, 0);
#pragma unroll
            for (int s = 1; s < 4; ++s)
                acc = __builtin_amdgcn_mfma_f32_32x32x16_bf16(eh[s], zh[q][s], acc, 0, 0, 0);
            // exact max (associative); triples fuse to v_max3
            const float g0 = fmaxf(fmaxf(acc[0],  acc[1]),  acc[2]);
            const float g1 = fmaxf(fmaxf(acc[3],  acc[4]),  acc[5]);
            const float g2 = fmaxf(fmaxf(acc[6],  acc[7]),  acc[8]);
            const float g3 = fmaxf(fmaxf(acc[9],  acc[10]), acc[11]);
            const float g4 = fmaxf(fmaxf(acc[12], acc[13]), acc[14]);
            const float h0 = fmaxf(fmaxf(g0, g1), g2);
            const float h1 = fmaxf(fmaxf(g3, g4), acc[15]);
            float tm = fmaxf(h0, h1);
            tm = fmaxf(tm, __shfl_xor(tm, 32));                  // combine halves
            macc[q] = fmaxf(macc[q], tm);
            if (half == 0) {
                const int tok = (ttb + q) * 32 + col;            // 128B contiguous store
                pmax32[(size_t)(ct0 + it) * tokens + tok] = tm;
            }
        }
    }

    if (half == 1) {    // macc identical in both halves post-shfl; parallel store lanes
#pragma unroll
        for (int q = 0; q < 4; ++q) {
            const int tok = (ttb + q) * 32 + col;
            pslice_t[(size_t)tok * 64 + blockIdx.y] = macc[q];
        }
    }
}

// ---------------- np-exact refine: in-kernel candidate derivation -------------------
// 8 tokens/block (4 waves x 2 half-wave groups). Per 32-lane group (one token):
// pslice_t row (256B contiguous) -> shfl-max -> thv; ballot qualifying slices; per
// qualifying slice read its 8 pmax32 -> ballot qualifying ctiles. embT4 loads
// 512B-contiguous; chains/order bit-identical to lineage. Indices bounded.
__global__ __launch_bounds__(256) void k_refine_ct(const float4* __restrict__ embT4,
                                                   const float* __restrict__ emb,
                                                   const float* __restrict__ zp32,
                                                   const float* __restrict__ A32,
                                                   const float* __restrict__ B32,
                                                   const float* __restrict__ pslice_t,
                                                   const float* __restrict__ pmax32,
                                                   int tokens, int CT, int K,
                                                   int* __restrict__ idx,
                                                   float* __restrict__ out_idx,
                                                   double* __restrict__ ploss) {
    #pragma clang fp contract(off)
    __shared__ __align__(16) float zps[8 * 64];
    __shared__ int s_cand[8][CMAX];
    const int tid = threadIdx.x;
    const int tbase = blockIdx.x * 8;
    for (int i = tid; i < 512; i += 256) zps[i] = zp32[(size_t)tbase * 64 + i];
    __syncthreads();

    const int w   = tid >> 6;
    const int ln  = tid & 31;
    const int sub = (tid >> 5) & 1;
    const int g   = w * 2 + sub;
    const int t   = tbase + g;
    const int shift = sub * 32;                   // this group's lanes in 64b ballots

    const float sv0 = pslice_t[(size_t)t * 64 + ln];
    const float sv1 = pslice_t[(size_t)t * 64 + 32 + ln];
    float m = fmaxf(sv0, sv1);
#pragma unroll
    for (int off = 16; off; off >>= 1) m = fmaxf(m, __shfl_xor(m, off, 32));
    const float thv = m - VWIN;

    const unsigned q0 = (unsigned)(__ballot(sv0 >= thv) >> shift);
    const unsigned q1 = (unsigned)(__ballot(sv1 >= thv) >> shift);
    unsigned long long qs = (unsigned long long)q0 | ((unsigned long long)q1 << 32);

    int ncand = 0;
    while (qs) {
        const int s = __builtin_ctzll(qs);
        qs &= qs - 1;
        float pv = -3.0e38f;
        if (ln < 8) pv = pmax32[(size_t)(s * 8 + ln) * tokens + t];
        unsigned cm = (unsigned)(__ballot(pv >= thv) >> shift) & 0xffu;
        while (cm) {
            const int c = __builtin_ctz(cm);
            cm &= cm - 1;
            if (ncand < CMAX && ln == 0) s_cand[g][ncand] = s * 8 + c;
            ++ncand;
        }
    }

    const bool full = (ncand > CMAX);             // overflow: scan all (winner present)
    const int iters = full ? CT : ncand;

    const float A = A32[t];
    const float* zp = zps + g * 64;

    float best = 3.0e38f;
    int bj = 0x7fffffff;
    for (int i = 0; i < iters; ++i) {
        const int ct = full ? i : s_cand[g][i];
        const int j  = ct * 32 + ln;              // ascending over i (cand ascending)
        const float Bj = B32[j];
        float l0 = 0.f, l1 = 0.f, l2 = 0.f, l3 = 0.f;
#pragma unroll
        for (int m4 = 0; m4 < 16; ++m4) {
            const float4 ev = embT4[(size_t)m4 * K + j];
            const float4 zv = *(const float4*)(zp + m4 * 4);
            l0 += zv.x * ev.x;
            l1 += zv.y * ev.y;
            l2 += zv.z * ev.z;
            l3 += zv.w * ev.w;
        }
        const float M = (l0 + l1) + (l2 + l3);
        const float S = A + Bj;
        const float d = S - 2.f * M;
        if (d < best) { best = d; bj = j; }       // strict < => first index
    }

#pragma unroll
    for (int off = 16; off; off >>= 1) {          // lex-min (d, j) within 32-group
        const float od = __shfl_xor(best, off, 32);
        const int   oj = __shfl_xor(bj, off, 32);
        if (od < best || (od == best && oj < bj)) { best = od; bj = oj; }
    }
    if ((unsigned)bj >= (unsigned)K) bj = 0;      // replay-poison guard (no-op live)

    // parallel loss for winner (tolerance-bound; double tree reduce)
    const float e0 = emb[(size_t)bj * 64 + ln];
    const float e1 = emb[(size_t)bj * 64 + 32 + ln];
    const float df0 = e0 - zp[ln];
    const float df1 = e1 - zp[32 + ln];
    double ls = (double)df0 * (double)df0 + (double)df1 * (double)df1;
#pragma unroll
    for (int off = 16; off; off >>= 1) ls += __shfl_xor(ls, off, 32);

    if (ln == 0) {
        idx[t] = bj;
        out_idx[t] = (float)bj;
        ploss[t] = ls;
    }
}

// ---------------- out v3: DOUT=256, CD=64, Wp row in VGPRs, 32 tokens/block ---------
// 4x fewer blocks than v2: the 64KB Wp->VGPR prologue amortized 4x (L2 Wp traffic
// 64MB -> 16MB). Block 0 additionally folds the loss reduction.
__global__ __launch_bounds__(256) void k_out_v2(const float* __restrict__ emb,
                                                const float* __restrict__ zp32,
                                                const int* __restrict__ idx,
                                                const float* __restrict__ Wp,
                                                const float* __restrict__ bp,
                                                float* __restrict__ out,
                                                const double* __restrict__ ploss,
                                                float* __restrict__ out_loss,
                                                int tokens, int K,
                                                double denom, int do_loss) {
    __shared__ float zq[32 * 64];
    __shared__ double red[256];
    const int tid = threadIdx.x;
    const int tbase = blockIdx.x * 32;
    for (int i = tid; i < 2048; i += 256) {
        const int tk = i >> 6, c = i & 63;
        const int t = tbase + tk;
        int k = idx[t];
        if ((unsigned)k >= (unsigned)K) k = 0;    // replay-poison guard (no-op live)
        const float zpv = zp32[(size_t)t * 64 + c];
        zq[i] = zpv + (emb[(size_t)k * 64 + c] - zpv);
    }
    float4 wp[16];
#pragma unroll
    for (int i = 0; i < 16; ++i) wp[i] = *(const float4*)(Wp + (size_t)tid * 64 + i * 4);
    const float bpd = bp[tid];
    __syncthreads();
#pragma unroll 4
    for (int tk = 0; tk < 32; ++tk) {
        const float* zr = zq + tk * 64;
        float acc = 0.f;
#pragma unroll
        for (int i = 0; i < 16; ++i) {
            const float4 p = *(const float4*)(zr + i * 4);
            acc += p.x * wp[i].x + p.y * wp[i].y + p.z * wp[i].z + p.w * wp[i].w;
        }
        out[(size_t)(tbase + tk) * 256 + tid] = acc + bpd;
    }
    if (do_loss && blockIdx.x == 0) {
        double a = 0.0;
        for (int i = tid; i < tokens; i += 256) a += ploss[i];
        red[tid] = a;
        __syncthreads();
        for (int s = 128; s > 0; s >>= 1) {
            if (tid < s) red[tid] += red[tid + s];
            __syncthreads();
        }
        if (tid == 0) *out_loss = (float)(1.25 * red[0] / denom);
    }
}

// standalone loss reduce (corner: fast path but k_out_v2 shape mismatch)
__global__ __launch_bounds__(256) void k_loss_red(const double* __restrict__ ploss,
                                                  float* __restrict__ out_loss,
                                                  int tokens, double denom) {
    __shared__ double red[256];
    double a = 0.0;
    for (int i = threadIdx.x; i < tokens; i += 256) a += ploss[i];
    red[threadIdx.x] = a;
    __syncthreads();
    for (int s = 128; s > 0; s >>= 1) {
        if (threadIdx.x < s) red[threadIdx.x] += red[threadIdx.x + s];
        __syncthreads();
    }
    if (threadIdx.x == 0) *out_loss = (float)(1.25 * red[0] / denom);
}

// =============================== fallback kernels ===================================
__global__ __launch_bounds__(64) void k_zp_np(const float* __restrict__ z,
                                              const float* __restrict__ Wq,
                                              const float* __restrict__ bq,
                                              float* __restrict__ zp32,
                                              int DIN, int CD) {
    #pragma clang fp contract(off)
    extern __shared__ float zl[];
    const int t = blockIdx.x;
    const int tid = threadIdx.x;
    for (int i = tid; i < DIN; i += 64) zl[i] = z[(size_t)t * DIN + i];
    __syncthreads();
    const int main8 = DIN & ~7;
    for (int c = tid; c < CD; c += 64) {
        const float* wr = Wq + (size_t)c * DIN;
        float l0 = 0.f, l1 = 0.f, l2 = 0.f, l3 = 0.f;
        for (int m = 0; m < main8; m += 4) {
            l0 += zl[m]     * wr[m];
            l1 += zl[m + 1] * wr[m + 1];
            l2 += zl[m + 2] * wr[m + 2];
            l3 += zl[m + 3] * wr[m + 3];
        }
        float acc = (l0 + l1) + (l2 + l3);
        for (int i = main8; i < DIN; ++i) acc += zl[i] * wr[i];
        zp32[(size_t)t * CD + c] = acc + bq[c];
    }
}

__global__ __launch_bounds__(256) void k_rowsum2_np(const float* __restrict__ src,
                                                    float* __restrict__ dst,
                                                    int rows) {
    #pragma clang fp contract(off)
    const int r = blockIdx.x * 256 + threadIdx.x;
    if (r >= rows) return;
    dst[r] = np_pairwise64_sq(src + (size_t)r * 64);
}

__global__ __launch_bounds__(256) void k_rowsum2_gen(const float* __restrict__ src,
                                                     float* __restrict__ dst,
                                                     int rows, int CD) {
    #pragma clang fp contract(off)
    const int r = blockIdx.x * 256 + threadIdx.x;
    if (r >= rows) return;
    const float* p = src + (size_t)r * CD;
    if (CD < 8) {
        float a = 0.f;
        for (int i = 0; i < CD; ++i) a += p[i] * p[i];
        dst[r] = a;
        return;
    }
    float acc[8];
#pragma unroll
    for (int j = 0; j < 8; ++j) acc[j] = p[j] * p[j];
    const int main8 = CD & ~7;
    for (int i = 8; i < main8; i += 8)
#pragma unroll
        for (int j = 0; j < 8; ++j) acc[j] += p[i + j] * p[i + j];
    float res = ((acc[0] + acc[1]) + (acc[2] + acc[3])) + ((acc[4] + acc[5]) + (acc[6] + acc[7]));
    for (int i = main8; i < CD; ++i) res += p[i] * p[i];
    dst[r] = res;
}

__global__ __launch_bounds__(256) void k_scan_gen(const float* __restrict__ emb,
                                                  const float* __restrict__ zp32,
                                                  const float* __restrict__ A32,
                                                  const float* __restrict__ B32,
                                                  int* __restrict__ idx,
                                                  float* __restrict__ out_idx,
                                                  int K, int CD) {
    #pragma clang fp contract(off)
    extern __shared__ float sm[];
    float* zp = sm;
    float* rm = zp + CD;
    int*   rj = (int*)(rm + 256);
    const int t = blockIdx.x;
    const int tid = threadIdx.x;
    for (int i = tid; i < CD; i += 256) zp[i] = zp32[(size_t)t * CD + i];
    __syncthreads();
    const float A = A32[t];
    float m1 = 3.0e38f; int j1 = 0x7fffffff;
    const int main8 = CD & ~7;
    for (int k = tid; k < K; k += 256) {
        const float* e = emb + (size_t)k * CD;
        float l0 = 0.f, l1 = 0.f, l2 = 0.f, l3 = 0.f;
        for (int m = 0; m < main8; m += 4) {
            l0 += zp[m]     * e[m];
            l1 += zp[m + 1] * e[m + 1];
            l2 += zp[m + 2] * e[m + 2];
            l3 += zp[m + 3] * e[m + 3];
        }
        float M = (l0 + l1) + (l2 + l3);
        for (int i = main8; i < CD; ++i) M += zp[i] * e[i];
        float S = A + B32[k];
        float d = S - 2.f * M;
        if (d < m1) { m1 = d; j1 = k; }
    }
    rm[tid] = m1; rj[tid] = j1;
    __syncthreads();
    if (tid == 0) {
        float gm = 3.0e38f; int gj = 0x7fffffff;
        for (int s = 0; s < 256; ++s) {
            if (rm[s] < gm || (rm[s] == gm && rj[s] < gj)) { gm = rm[s]; gj = rj[s]; }
        }
        idx[t] = gj;
        out_idx[t] = (float)gj;
    }
}

__global__ __launch_bounds__(256) void k_out(const float* __restrict__ emb,
                                             const float* __restrict__ zp32,
                                             const int* __restrict__ idx,
                                             const float* __restrict__ Wp,
                                             const float* __restrict__ bp,
                                             float* __restrict__ out,
                                             int DOUT, int CD) {
    extern __shared__ float zq[];
    const int t = blockIdx.x;
    const int tid = threadIdx.x;
    const int k = idx[t];
    for (int i = tid; i < CD; i += 256) {
        const float zpv = zp32[(size_t)t * CD + i];
        zq[i] = zpv + (emb[(size_t)k * CD + i] - zpv);
    }
    __syncthreads();
    for (int d = tid; d < DOUT; d += 256) {
        const float* w = Wp + (size_t)d * CD;
        float acc = 0.f;
        for (int c = 0; c < CD; ++c) acc += zq[c] * w[c];
        out[(size_t)t * DOUT + d] = acc + bp[d];
    }
}

__global__ __launch_bounds__(256) void k_loss1(const float* __restrict__ zp32,
                                               const float* __restrict__ emb,
                                               const int* __restrict__ idx,
                                               double* __restrict__ part,
                                               long long total, int CD) {
    double acc = 0.0;
    const long long stride = (long long)gridDim.x * 256;
    for (long long e = (long long)blockIdx.x * 256 + threadIdx.x; e < total; e += stride) {
        const long long t = e / CD;
        const int c = (int)(e - t * CD);
        const float df = emb[(size_t)idx[t] * CD + c] - zp32[e];
        acc += (double)df * (double)df;
    }
    __shared__ double red[256];
    red[threadIdx.x] = acc;
    __syncthreads();
    for (int s = 128; s > 0; s >>= 1) {
        if (threadIdx.x < s) red[threadIdx.x] += red[threadIdx.x + s];
        __syncthreads();
    }
    if (threadIdx.x == 0) part[blockIdx.x] = red[0];
}

__global__ __launch_bounds__(256) void k_loss2(const double* __restrict__ part,
                                               float* __restrict__ out_loss,
                                               double denom, int n) {
    __shared__ double red[256];
    const int tid = threadIdx.x;
    red[tid] = (tid < n) ? part[tid] : 0.0;
    __syncthreads();
    for (int s = 128; s > 0; s >>= 1) {
        if (tid < s) red[tid] += red[tid + s];
        __syncthreads();
    }
    if (tid == 0) *out_loss = (float)(1.25 * red[0] / denom);
}

extern "C" void kernel_launch(void* const* d_in, const int* in_sizes, int n_in,
                              void* d_out, int out_size, void* d_ws, size_t ws_size,
                              hipStream_t stream) {
    const float* z   = (const float*)d_in[0];
    const float* Wq  = (const float*)d_in[1];
    const float* bq  = (const float*)d_in[2];
    const float* emb = (const float*)d_in[3];
    const float* Wp  = (const float*)d_in[4];
    const float* bp  = (const float*)d_in[5];

    const int CD   = in_sizes[2];
    const int DIN  = in_sizes[1] / CD;
    const int DOUT = in_sizes[5];
    const int K    = in_sizes[3] / CD;
    const long long T = (long long)in_sizes[0] / DIN;

    float* out      = (float*)d_out;
    float* out_idx  = out + (size_t)T * DOUT;
    float* out_loss = out_idx + T;

    char* ws = (char*)d_ws;
    size_t off = 0;
    auto carve = [&](size_t bytes) -> char* {
        char* p = ws + off;
        off = (off + bytes + 255) & ~(size_t)255;
        return p;
    };
    float*  zp32  = (float*)carve((size_t)T * CD * 4);
    float*  A32   = (float*)carve((size_t)T * 4);
    float*  B32   = (float*)carve((size_t)K * 4);
    int*    idx   = (int*)carve((size_t)T * 4);
    double* part  = (double*)carve(128 * 8);
    double* ploss = (double*)carve((size_t)T * 8);

    // fast path: merged prep + 1 MFMA scan (ctile+slice maxima) + refine + out
    bool fast = (CD == 64) && (DIN == 256) && (K % 2048 == 0) && (K <= 16384) &&
                (T % 512 == 0);
    short8v* zpf = nullptr; short8v* ef = nullptr;
    float* bfl = nullptr; float* pmax32 = nullptr; float* pslice_t = nullptr;
    float4* embT4 = nullptr;
    const int NSLICE = 64;
    const int CT = K / 32;
    if (fast) {
        const int ztiles = (int)(T / 32);
        const int ctiles = CT;
        zpf      = (short8v*)carve((size_t)ztiles * 256 * 16);
        ef       = (short8v*)carve((size_t)ctiles * 256 * 16);
        bfl      = (float*)carve((size_t)ctiles * 32 * 4);
        pmax32   = (float*)carve((size_t)CT * T * 4);
        pslice_t = (float*)carve((size_t)T * NSLICE * 4);
        embT4    = (float4*)carve((size_t)K * 64 * 4);
        if (off > ws_size) fast = false;
    }

    if (fast) {
        const int tokblocks  = (int)(T / 32);
        const int codeblocks = K / 64;
        k_prep<<<dim3((unsigned)(tokblocks + codeblocks)), dim3(512), 0, stream>>>(
            z, Wq, bq, emb, zp32, A32, zpf, B32, ef, bfl, embT4, tokblocks, K);

        dim3 grid((unsigned)(T / 512), NSLICE);
        k_scan_max<<<grid, dim3(256), 0, stream>>>(zpf, ef, bfl, pmax32, pslice_t,
                                                   (int)T, K);

        k_refine_ct<<<dim3((unsigned)(T / 8)), dim3(256), 0, stream>>>(
            embT4, emb, zp32, A32, B32, pslice_t, pmax32, (int)T, CT, K,
            idx, out_idx, ploss);

        if (DOUT == 256 && T % 32 == 0) {
            k_out_v2<<<dim3((unsigned)(T / 32)), dim3(256), 0, stream>>>(
                emb, zp32, idx, Wp, bp, out, ploss, out_loss, (int)T, K,
                (double)T * CD, 1);
        } else {
            k_loss_red<<<dim3(1), dim3(256), 0, stream>>>(ploss, out_loss, (int)T,
                                                          (double)T * CD);
            k_out<<<dim3((unsigned)T), dim3(256), (size_t)CD * 4, stream>>>(
                emb, zp32, idx, Wp, bp, out, DOUT, CD);
        }
    } else {
        k_zp_np<<<dim3((unsigned)T), dim3(64), (size_t)DIN * 4, stream>>>(z, Wq, bq, zp32, DIN, CD);
        if (CD == 64)
            k_rowsum2_np<<<dim3((unsigned)((T + 255) / 256)), dim3(256), 0, stream>>>(zp32, A32, (int)T);
        else
            k_rowsum2_gen<<<dim3((unsigned)((T + 255) / 256)), dim3(256), 0, stream>>>(zp32, A32, (int)T, CD);
        if (CD == 64)
            k_rowsum2_np<<<dim3((K + 255) / 256), dim3(256), 0, stream>>>(emb, B32, K);
        else
            k_rowsum2_gen<<<dim3((K + 255) / 256), dim3(256), 0, stream>>>(emb, B32, K, CD);

        const size_t sm = (size_t)CD * 4 + 256 * 4 + 256 * 4;
        k_scan_gen<<<dim3((unsigned)T), dim3(256), sm, stream>>>(
            emb, zp32, A32, B32, idx, out_idx, K, CD);
        k_loss1<<<dim3(128), dim3(256), 0, stream>>>(zp32, emb, idx, part, (long long)T * CD, CD);
        k_loss2<<<dim3(1), dim3(256), 0, stream>>>(part, out_loss, (double)T * CD, 128);

        k_out<<<dim3((unsigned)T), dim3(256), (size_t)CD * 4, stream>>>(
            emb, zp32, idx, Wp, bp, out, DOUT, CD);
    }
}

// Round 8
// 135.947 us; speedup vs baseline: 1.0817x; 1.0817x over previous
//
#include <hip/hip_runtime.h>
#include <hip/hip_bf16.h>

// ===================================================================================
// Verified lineage (R6-R11, absmax 3.05e-5): argmin bit-replicates numpy-f32:
//   zp  = einsum SSE mod-4 accumulators, reduce (l0+l1)+(l2+l3), + bq
//   A,B = pairwise f32 row-sum-of-squares (AVX512 npyv tree for n=64)
//   d   = fl32( fl32(A + B_k) - fl32(2*M_k) ), first-index ties
// R20 (this round): FULL REVERT to the R17 verified build (138.0us, round-5 bench).
//   POST-MORTEM R19: hipLaunchCooperativeKernel inside kernel_launch breaks the
//   harness's graph capture (G9 / rigor.md tripwires) -> container failed twice.
//   The capability guard checked device support, not capture compatibility, and the
//   failure happened outside the interceptable error path. Lesson recorded: no coop
//   launches, no host-side queries, nothing but plain <<<>>> in kernel_launch.
//   This file is byte-identical in behavior to the R17 chain:
//     prep -> scan -> refine -> out  (4 launches)
//   - global_load_lds staging in scan (s_ef/s_bfl) and prep (z-tile)
//   - scan binit via 4 broadcast ds_read_b128 (bit-identical C-operand)
//   - max-reduce in v_max3-fusable triples (exact, associative)
//   - refine: pslice ballot -> pmax32 ballot -> exact dots via embT4 transpose
//   - out: 8 tok/block, Wp row in VGPRs, loss folded into block 0
//   Replay-poison guards kept (bounded indices; clamped idx).
// ===================================================================================

#define VWIN 1.0e-5f
#define CMAX 16

typedef short short8v __attribute__((ext_vector_type(8)));
typedef float floatx16 __attribute__((ext_vector_type(16)));

#ifndef __has_builtin
#define __has_builtin(x) 0
#endif
#if __has_builtin(__builtin_amdgcn_global_load_lds)
#define HAVE_GLL 1
#else
#define HAVE_GLL 0
#endif

// per-lane global src (already includes lane offset); wave-uniform LDS base.
__device__ __forceinline__ void stage16(const void* g, void* l, int lane) {
#if HAVE_GLL
    (void)lane;
    __builtin_amdgcn_global_load_lds(
        (const __attribute__((address_space(1))) void*)g,
        (__attribute__((address_space(3))) void*)l, 16, 0, 0);
#else
    ((float4*)l)[lane] = *(const float4*)g;
#endif
}
__device__ __forceinline__ void stage4(const void* g, void* l, int lane) {
#if HAVE_GLL
    (void)lane;
    __builtin_amdgcn_global_load_lds(
        (const __attribute__((address_space(1))) void*)g,
        (__attribute__((address_space(3))) void*)l, 4, 0, 0);
#else
    ((float*)l)[lane] = *(const float*)g;
#endif
}

__device__ __forceinline__ short f2bf(float x) {           // RTNE f32->bf16
    unsigned u = __builtin_bit_cast(unsigned, x);
    unsigned r = (u + 0x7fffu + ((u >> 16) & 1u)) >> 16;
    return (short)r;
}

__device__ __forceinline__ float np_pairwise64_sq(const float* __restrict__ p) {
    #pragma clang fp contract(off)
    float v[16];
#pragma unroll
    for (int j = 0; j < 16; ++j) {
        float x0 = p[j]      * p[j];
        float x1 = p[j + 32] * p[j + 32];
        float x2 = p[j + 16] * p[j + 16];
        float x3 = p[j + 48] * p[j + 48];
        float r0 = x0 + x1;
        float r1 = x2 + x3;
        v[j] = r0 + r1;
    }
    float s[8], t[4];
#pragma unroll
    for (int j = 0; j < 8; ++j) s[j] = v[j] + v[j + 8];
#pragma unroll
    for (int j = 0; j < 4; ++j) t[j] = s[j] + s[j + 4];
    return (t[0] + t[2]) + (t[1] + t[3]);
}

// ---------------- merged prep: tok blocks (bx < tokblocks) + code blocks ------------
// tok: CD=64, DIN=256, 32 tokens/block, 512 threads -> zp32 + A32 + zpf.
// code: 2 tiles (64 codes)/block, 256 threads each half -> B32 + ef + bfl + embT4.
__global__ __launch_bounds__(512) void k_prep(const float* __restrict__ z,
                                              const float* __restrict__ Wq,
                                              const float* __restrict__ bq,
                                              const float* __restrict__ emb,
                                              float* __restrict__ zp32,
                                              float* __restrict__ A32,
                                              short8v* __restrict__ zpf,
                                              float* __restrict__ B32,
                                              short8v* __restrict__ ef,
                                              float* __restrict__ bfl,
                                              float4* __restrict__ embT4,
                                              int tokblocks, int K) {
    __shared__ float pool[64 * 129 + 32 * 128 + 32 * 65];   // 57.7 KB
    const int tid = threadIdx.x;
    const int bx  = blockIdx.x;

    if (bx < tokblocks) {
        float* wq  = pool;                       // 64*129
        float* zl  = pool + 64 * 129;            // 32*128
        float* zps = zl + 32 * 128;              // 32*65
        const int w    = tid >> 6;
        const int lane = tid & 63;
        const int tbase = bx * 32;

        float l[4][4];
#pragma unroll
        for (int i = 0; i < 4; ++i)
#pragma unroll
            for (int j = 0; j < 4; ++j) l[i][j] = 0.f;

        for (int h = 0; h < 2; ++h) {
            __syncthreads();
            for (int i = tid; i < 64 * 128; i += 512) {
                const int c = i >> 7, m = i & 127;
                wq[c * 129 + m] = Wq[(size_t)c * 256 + h * 128 + m];
            }
            // z tile: 32x128 f32 = 1024 float4; dest linear -> global_load_lds.
            for (int b4 = w * 64; b4 < 1024; b4 += 512) {
                const int i4 = b4 + lane;
                const int t  = i4 >> 5, m4 = i4 & 31;
                stage16(z + (size_t)(tbase + t) * 256 + h * 128 + m4 * 4,
                        zl + (size_t)b4 * 4, lane);
            }
            __syncthreads();
            {
                #pragma clang fp contract(off)
                const float* wr  = wq + lane * 129;
                const float* zt0 = zl + (w * 4 + 0) * 128;
                const float* zt1 = zl + (w * 4 + 1) * 128;
                const float* zt2 = zl + (w * 4 + 2) * 128;
                const float* zt3 = zl + (w * 4 + 3) * 128;
                for (int m = 0; m < 128; m += 4) {
                    const float w0 = wr[m], w1 = wr[m + 1], w2 = wr[m + 2], w3 = wr[m + 3];
                    const float4 p0 = *(const float4*)(zt0 + m);
                    const float4 p1 = *(const float4*)(zt1 + m);
                    const float4 p2 = *(const float4*)(zt2 + m);
                    const float4 p3 = *(const float4*)(zt3 + m);
                    l[0][0] += p0.x * w0; l[0][1] += p0.y * w1; l[0][2] += p0.z * w2; l[0][3] += p0.w * w3;
                    l[1][0] += p1.x * w0; l[1][1] += p1.y * w1; l[1][2] += p1.z * w2; l[1][3] += p1.w * w3;
                    l[2][0] += p2.x * w0; l[2][1] += p2.y * w1; l[2][2] += p2.z * w2; l[2][3] += p2.w * w3;
                    l[3][0] += p3.x * w0; l[3][1] += p3.y * w1; l[3][2] += p3.z * w2; l[3][3] += p3.w * w3;
                }
            }
        }
        {
            #pragma clang fp contract(off)
            const float bqc = bq[lane];
#pragma unroll
            for (int tk = 0; tk < 4; ++tk) {
                const float acc = (l[tk][0] + l[tk][1]) + (l[tk][2] + l[tk][3]);
                const float zpv = acc + bqc;
                zp32[(size_t)(tbase + w * 4 + tk) * 64 + lane] = zpv;
                zps[(w * 4 + tk) * 65 + lane] = zpv;
            }
        }
        __syncthreads();
        if (tid < 32) A32[tbase + tid] = np_pairwise64_sq(zps + tid * 65);
        if (tid < 256) {
            const int fl = tid & 63;
            const int s  = tid >> 6;
            const int row = fl & 31;
            const int k0 = s * 16 + (fl >> 5) * 8;
            short8v hv;
            const float* p = zps + row * 65 + k0;
#pragma unroll
            for (int j = 0; j < 8; ++j) hv[j] = f2bf(p[j]);
            zpf[(size_t)(bx * 4 + s) * 64 + fl] = hv;
        }
    } else {
        const int half = tid >> 8;                    // 0/1: which tile this half handles
        const int ltid = tid & 255;
        const int tile = (bx - tokblocks) * 2 + half;
        float* et = pool + half * (32 * 65);

        for (int i = ltid; i < 2048; i += 256)
            et[(i >> 6) * 65 + (i & 63)] = emb[(size_t)tile * 2048 + i];
        __syncthreads();
        if (ltid < 32) {
            const float b = np_pairwise64_sq(et + ltid * 65);
            B32[tile * 32 + ltid] = b;
            // f32 image of bf16(-B/2): bit-identical to mfma(bfrag, ones, 0) init.
            const unsigned hb = (unsigned)(unsigned short)f2bf(-0.5f * b);
            bfl[tile * 32 + ltid] = __builtin_bit_cast(float, hb << 16);
        }
        {
            const int fl = ltid & 63;
            const int s  = ltid >> 6;
            const int row = fl & 31;
            const int k0 = s * 16 + (fl >> 5) * 8;
            short8v hv;
            const float* p = et + row * 65 + k0;
#pragma unroll
            for (int j = 0; j < 8; ++j) hv[j] = f2bf(p[j]);
            ef[(size_t)(tile * 4 + s) * 64 + fl] = hv;
        }
        // exact f32 transpose: embT4[m4][j] = emb[j][4*m4 .. 4*m4+3]
#pragma unroll
        for (int p = 0; p < 2; ++p) {
            const int id = ltid + (p << 8);
            const int m4 = id >> 5;                   // 0..15
            const int r  = id & 31;
            const float* q = et + r * 65 + m4 * 4;
            float4 v;
            v.x = q[0]; v.y = q[1]; v.z = q[2]; v.w = q[3];
            embT4[(size_t)m4 * K + tile * 32 + r] = v;
        }
    }
}

// ---------------- pass-1: per-(token, ctile) MAX of v = M - B/2 ---------------------
// grid (T/512, 64); block stages its etiles-ctile slice via global_load_lds.
// Bias enters as MFMA C-operand (4 broadcast b128 reads). pmax32[ct][tok] coalesced;
// pslice_t[tok][64] = per-slice max.
__global__ __launch_bounds__(256) void k_scan_max(const short8v* __restrict__ zpf,
                                                  const short8v* __restrict__ ef,
                                                  const float* __restrict__ bfl,
                                                  float* __restrict__ pmax32,
                                                  float* __restrict__ pslice_t,
                                                  int tokens, int K) {
    __shared__ __align__(16) short8v s_ef[2048];   // up to 8 ctiles x 4 x 64 (32 KB)
    __shared__ __align__(16) float s_bfl[256];     // up to 8 ctiles x 32 rows (1 KB)
    const int tid  = threadIdx.x;
    const int w    = tid >> 6;
    const int lane = tid & 63;
    const int half = lane >> 5;
    const int col  = lane & 31;
    const int ttb  = (blockIdx.x * 4 + w) * 4;
    const int etiles = K / 2048;                  // 8 for K=16384
    const int ct0 = blockIdx.y * etiles;

    for (int base = w * 64; base < etiles * 256; base += 256)
        stage16(&ef[(size_t)ct0 * 256 + base + lane], &s_ef[base], lane);
    {
        const int base = w * 64;
        if (base + lane < etiles * 32)
            stage4(&bfl[(size_t)ct0 * 32 + base + lane], &s_bfl[base], lane);
    }

    short8v zh[4][4];
#pragma unroll
    for (int q = 0; q < 4; ++q)
#pragma unroll
        for (int s = 0; s < 4; ++s) zh[q][s] = zpf[(size_t)((ttb + q) * 4 + s) * 64 + lane];

    __syncthreads();

    float macc[4] = {-3.0e38f, -3.0e38f, -3.0e38f, -3.0e38f};

    for (int it = 0; it < etiles; ++it) {
        short8v eh[4];
#pragma unroll
        for (int s = 0; s < 4; ++s) eh[s] = s_ef[it * 256 + s * 64 + lane];
        // binit[r] = s_bfl[it*32 + (r&3) + 8*(r>>2) + 4*half]; 4 broadcast b128 reads.
        const float4 b0 = *(const float4*)(s_bfl + it * 32 +  0 + 4 * half);
        const float4 b1 = *(const float4*)(s_bfl + it * 32 +  8 + 4 * half);
        const float4 b2 = *(const float4*)(s_bfl + it * 32 + 16 + 4 * half);
        const float4 b3 = *(const float4*)(s_bfl + it * 32 + 24 + 4 * half);
        floatx16 binit;
        binit[0]  = b0.x; binit[1]  = b0.y; binit[2]  = b0.z; binit[3]  = b0.w;
        binit[4]  = b1.x; binit[5]  = b1.y; binit[6]  = b1.z; binit[7]  = b1.w;
        binit[8]  = b2.x; binit[9]  = b2.y; binit[10] = b2.z; binit[11] = b2.w;
        binit[12] = b3.x; binit[13] = b3.y; binit[14] = b3.z; binit[15] = b3.w;
#pragma unroll
        for (int q = 0; q < 4; ++q) {
            floatx16 acc = __builtin_amdgcn_mfma_f32_32x32x16_bf16(eh[0], zh[q][0], binit, 0, 0, 0);
#pragma unroll
            for (int s = 1; s < 4; ++s)
                acc = __builtin_amdgcn_mfma_f32_32x32x16_bf16(eh[s], zh[q][s], acc, 0, 0, 0);
            // exact max (associative); triples fuse to v_max3
            const float g0 = fmaxf(fmaxf(acc[0],  acc[1]),  acc[2]);
            const float g1 = fmaxf(fmaxf(acc[3],  acc[4]),  acc[5]);
            const float g2 = fmaxf(fmaxf(acc[6],  acc[7]),  acc[8]);
            const float g3 = fmaxf(fmaxf(acc[9],  acc[10]), acc[11]);
            const float g4 = fmaxf(fmaxf(acc[12], acc[13]), acc[14]);
            const float h0 = fmaxf(fmaxf(g0, g1), g2);
            const float h1 = fmaxf(fmaxf(g3, g4), acc[15]);
            float tm = fmaxf(h0, h1);
            tm = fmaxf(tm, __shfl_xor(tm, 32));                  // combine halves
            macc[q] = fmaxf(macc[q], tm);
            if (half == 0) {
                const int tok = (ttb + q) * 32 + col;            // 128B contiguous store
                pmax32[(size_t)(ct0 + it) * tokens + tok] = tm;
            }
        }
    }

    if (half == 0) {
#pragma unroll
        for (int q = 0; q < 4; ++q) {
            const int tok = (ttb + q) * 32 + col;
            pslice_t[(size_t)tok * 64 + blockIdx.y] = macc[q];
        }
    }
}

// ---------------- np-exact refine: in-kernel candidate derivation -------------------
// 8 tokens/block (4 waves x 2 half-wave groups). Per 32-lane group (one token):
// pslice_t row (256B contiguous) -> shfl-max -> thv; ballot qualifying slices; per
// qualifying slice read its 8 pmax32 -> ballot qualifying ctiles. embT4 loads
// 512B-contiguous; chains/order bit-identical to lineage. Indices bounded.
__global__ __launch_bounds__(256) void k_refine_ct(const float4* __restrict__ embT4,
                                                   const float* __restrict__ emb,
                                                   const float* __restrict__ zp32,
                                                   const float* __restrict__ A32,
                                                   const float* __restrict__ B32,
                                                   const float* __restrict__ pslice_t,
                                                   const float* __restrict__ pmax32,
                                                   int tokens, int CT, int K,
                                                   int* __restrict__ idx,
                                                   float* __restrict__ out_idx,
                                                   double* __restrict__ ploss) {
    #pragma clang fp contract(off)
    __shared__ __align__(16) float zps[8 * 64];
    __shared__ int s_cand[8][CMAX];
    const int tid = threadIdx.x;
    const int tbase = blockIdx.x * 8;
    for (int i = tid; i < 512; i += 256) zps[i] = zp32[(size_t)tbase * 64 + i];
    __syncthreads();

    const int w   = tid >> 6;
    const int ln  = tid & 31;
    const int sub = (tid >> 5) & 1;
    const int g   = w * 2 + sub;
    const int t   = tbase + g;
    const int shift = sub * 32;                   // this group's lanes in 64b ballots

    const float sv0 = pslice_t[(size_t)t * 64 + ln];
    const float sv1 = pslice_t[(size_t)t * 64 + 32 + ln];
    float m = fmaxf(sv0, sv1);
#pragma unroll
    for (int off = 16; off; off >>= 1) m = fmaxf(m, __shfl_xor(m, off, 32));
    const float thv = m - VWIN;

    const unsigned q0 = (unsigned)(__ballot(sv0 >= thv) >> shift);
    const unsigned q1 = (unsigned)(__ballot(sv1 >= thv) >> shift);
    unsigned long long qs = (unsigned long long)q0 | ((unsigned long long)q1 << 32);

    int ncand = 0;
    while (qs) {
        const int s = __builtin_ctzll(qs);
        qs &= qs - 1;
        float pv = -3.0e38f;
        if (ln < 8) pv = pmax32[(size_t)(s * 8 + ln) * tokens + t];
        unsigned cm = (unsigned)(__ballot(pv >= thv) >> shift) & 0xffu;
        while (cm) {
            const int c = __builtin_ctz(cm);
            cm &= cm - 1;
            if (ncand < CMAX && ln == 0) s_cand[g][ncand] = s * 8 + c;
            ++ncand;
        }
    }

    const bool full = (ncand > CMAX);             // overflow: scan all (winner present)
    const int iters = full ? CT : ncand;

    const float A = A32[t];
    const float* zp = zps + g * 64;

    float best = 3.0e38f;
    int bj = 0x7fffffff;
    for (int i = 0; i < iters; ++i) {
        const int ct = full ? i : s_cand[g][i];
        const int j  = ct * 32 + ln;              // ascending over i (cand ascending)
        const float Bj = B32[j];
        float l0 = 0.f, l1 = 0.f, l2 = 0.f, l3 = 0.f;
#pragma unroll
        for (int m4 = 0; m4 < 16; ++m4) {
            const float4 ev = embT4[(size_t)m4 * K + j];
            const float4 zv = *(const float4*)(zp + m4 * 4);
            l0 += zv.x * ev.x;
            l1 += zv.y * ev.y;
            l2 += zv.z * ev.z;
            l3 += zv.w * ev.w;
        }
        const float M = (l0 + l1) + (l2 + l3);
        const float S = A + Bj;
        const float d = S - 2.f * M;
        if (d < best) { best = d; bj = j; }       // strict < => first index
    }

#pragma unroll
    for (int off = 16; off; off >>= 1) {          // lex-min (d, j) within 32-group
        const float od = __shfl_xor(best, off, 32);
        const int   oj = __shfl_xor(bj, off, 32);
        if (od < best || (od == best && oj < bj)) { best = od; bj = oj; }
    }
    if ((unsigned)bj >= (unsigned)K) bj = 0;      // replay-poison guard (no-op live)

    // parallel loss for winner (tolerance-bound; double tree reduce)
    const float e0 = emb[(size_t)bj * 64 + ln];
    const float e1 = emb[(size_t)bj * 64 + 32 + ln];
    const float df0 = e0 - zp[ln];
    const float df1 = e1 - zp[32 + ln];
    double ls = (double)df0 * (double)df0 + (double)df1 * (double)df1;
#pragma unroll
    for (int off = 16; off; off >>= 1) ls += __shfl_xor(ls, off, 32);

    if (ln == 0) {
        idx[t] = bj;
        out_idx[t] = (float)bj;
        ploss[t] = ls;
    }
}

// ---------------- out v2: DOUT=256, CD=64, Wp row in VGPRs, 8 tokens/block ----------
// block 0 additionally folds the loss reduction (hidden under the other blocks).
__global__ __launch_bounds__(256) void k_out_v2(const float* __restrict__ emb,
                                                const float* __restrict__ zp32,
                                                const int* __restrict__ idx,
                                                const float* __restrict__ Wp,
                                                const float* __restrict__ bp,
                                                float* __restrict__ out,
                                                const double* __restrict__ ploss,
                                                float* __restrict__ out_loss,
                                                int tokens, int K,
                                                double denom, int do_loss) {
    __shared__ float zq[8 * 64];
    __shared__ double red[256];
    const int tid = threadIdx.x;
    const int tbase = blockIdx.x * 8;
    for (int i = tid; i < 512; i += 256) {
        const int tk = i >> 6, c = i & 63;
        const int t = tbase + tk;
        int k = idx[t];
        if ((unsigned)k >= (unsigned)K) k = 0;    // replay-poison guard (no-op live)
        const float zpv = zp32[(size_t)t * 64 + c];
        zq[i] = zpv + (emb[(size_t)k * 64 + c] - zpv);
    }
    float4 wp[16];
#pragma unroll
    for (int i = 0; i < 16; ++i) wp[i] = *(const float4*)(Wp + (size_t)tid * 64 + i * 4);
    const float bpd = bp[tid];
    __syncthreads();
#pragma unroll
    for (int tk = 0; tk < 8; ++tk) {
        const float* zr = zq + tk * 64;
        float acc = 0.f;
#pragma unroll
        for (int i = 0; i < 16; ++i) {
            const float4 p = *(const float4*)(zr + i * 4);
            acc += p.x * wp[i].x + p.y * wp[i].y + p.z * wp[i].z + p.w * wp[i].w;
        }
        out[(size_t)(tbase + tk) * 256 + tid] = acc + bpd;
    }
    if (do_loss && blockIdx.x == 0) {
        double a = 0.0;
        for (int i = tid; i < tokens; i += 256) a += ploss[i];
        red[tid] = a;
        __syncthreads();
        for (int s = 128; s > 0; s >>= 1) {
            if (tid < s) red[tid] += red[tid + s];
            __syncthreads();
        }
        if (tid == 0) *out_loss = (float)(1.25 * red[0] / denom);
    }
}

// standalone loss reduce (corner: fast path but k_out_v2 shape mismatch)
__global__ __launch_bounds__(256) void k_loss_red(const double* __restrict__ ploss,
                                                  float* __restrict__ out_loss,
                                                  int tokens, double denom) {
    __shared__ double red[256];
    double a = 0.0;
    for (int i = threadIdx.x; i < tokens; i += 256) a += ploss[i];
    red[threadIdx.x] = a;
    __syncthreads();
    for (int s = 128; s > 0; s >>= 1) {
        if (threadIdx.x < s) red[threadIdx.x] += red[threadIdx.x + s];
        __syncthreads();
    }
    if (threadIdx.x == 0) *out_loss = (float)(1.25 * red[0] / denom);
}

// =============================== fallback kernels ===================================
__global__ __launch_bounds__(64) void k_zp_np(const float* __restrict__ z,
                                              const float* __restrict__ Wq,
                                              const float* __restrict__ bq,
                                              float* __restrict__ zp32,
                                              int DIN, int CD) {
    #pragma clang fp contract(off)
    extern __shared__ float zl[];
    const int t = blockIdx.x;
    const int tid = threadIdx.x;
    for (int i = tid; i < DIN; i += 64) zl[i] = z[(size_t)t * DIN + i];
    __syncthreads();
    const int main8 = DIN & ~7;
    for (int c = tid; c < CD; c += 64) {
        const float* wr = Wq + (size_t)c * DIN;
        float l0 = 0.f, l1 = 0.f, l2 = 0.f, l3 = 0.f;
        for (int m = 0; m < main8; m += 4) {
            l0 += zl[m]     * wr[m];
            l1 += zl[m + 1] * wr[m + 1];
            l2 += zl[m + 2] * wr[m + 2];
            l3 += zl[m + 3] * wr[m + 3];
        }
        float acc = (l0 + l1) + (l2 + l3);
        for (int i = main8; i < DIN; ++i) acc += zl[i] * wr[i];
        zp32[(size_t)t * CD + c] = acc + bq[c];
    }
}

__global__ __launch_bounds__(256) void k_rowsum2_np(const float* __restrict__ src,
                                                    float* __restrict__ dst,
                                                    int rows) {
    #pragma clang fp contract(off)
    const int r = blockIdx.x * 256 + threadIdx.x;
    if (r >= rows) return;
    dst[r] = np_pairwise64_sq(src + (size_t)r * 64);
}

__global__ __launch_bounds__(256) void k_rowsum2_gen(const float* __restrict__ src,
                                                     float* __restrict__ dst,
                                                     int rows, int CD) {
    #pragma clang fp contract(off)
    const int r = blockIdx.x * 256 + threadIdx.x;
    if (r >= rows) return;
    const float* p = src + (size_t)r * CD;
    if (CD < 8) {
        float a = 0.f;
        for (int i = 0; i < CD; ++i) a += p[i] * p[i];
        dst[r] = a;
        return;
    }
    float acc[8];
#pragma unroll
    for (int j = 0; j < 8; ++j) acc[j] = p[j] * p[j];
    const int main8 = CD & ~7;
    for (int i = 8; i < main8; i += 8)
#pragma unroll
        for (int j = 0; j < 8; ++j) acc[j] += p[i + j] * p[i + j];
    float res = ((acc[0] + acc[1]) + (acc[2] + acc[3])) + ((acc[4] + acc[5]) + (acc[6] + acc[7]));
    for (int i = main8; i < CD; ++i) res += p[i] * p[i];
    dst[r] = res;
}

__global__ __launch_bounds__(256) void k_scan_gen(const float* __restrict__ emb,
                                                  const float* __restrict__ zp32,
                                                  const float* __restrict__ A32,
                                                  const float* __restrict__ B32,
                                                  int* __restrict__ idx,
                                                  float* __restrict__ out_idx,
                                                  int K, int CD) {
    #pragma clang fp contract(off)
    extern __shared__ float sm[];
    float* zp = sm;
    float* rm = zp + CD;
    int*   rj = (int*)(rm + 256);
    const int t = blockIdx.x;
    const int tid = threadIdx.x;
    for (int i = tid; i < CD; i += 256) zp[i] = zp32[(size_t)t * CD + i];
    __syncthreads();
    const float A = A32[t];
    float m1 = 3.0e38f; int j1 = 0x7fffffff;
    const int main8 = CD & ~7;
    for (int k = tid; k < K; k += 256) {
        const float* e = emb + (size_t)k * CD;
        float l0 = 0.f, l1 = 0.f, l2 = 0.f, l3 = 0.f;
        for (int m = 0; m < main8; m += 4) {
            l0 += zp[m]     * e[m];
            l1 += zp[m + 1] * e[m + 1];
            l2 += zp[m + 2] * e[m + 2];
            l3 += zp[m + 3] * e[m + 3];
        }
        float M = (l0 + l1) + (l2 + l3);
        for (int i = main8; i < CD; ++i) M += zp[i] * e[i];
        float S = A + B32[k];
        float d = S - 2.f * M;
        if (d < m1) { m1 = d; j1 = k; }
    }
    rm[tid] = m1; rj[tid] = j1;
    __syncthreads();
    if (tid == 0) {
        float gm = 3.0e38f; int gj = 0x7fffffff;
        for (int s = 0; s < 256; ++s) {
            if (rm[s] < gm || (rm[s] == gm && rj[s] < gj)) { gm = rm[s]; gj = rj[s]; }
        }
        idx[t] = gj;
        out_idx[t] = (float)gj;
    }
}

__global__ __launch_bounds__(256) void k_out(const float* __restrict__ emb,
                                             const float* __restrict__ zp32,
                                             const int* __restrict__ idx,
                                             const float* __restrict__ Wp,
                                             const float* __restrict__ bp,
                                             float* __restrict__ out,
                                             int DOUT, int CD) {
    extern __shared__ float zq[];
    const int t = blockIdx.x;
    const int tid = threadIdx.x;
    const int k = idx[t];
    for (int i = tid; i < CD; i += 256) {
        const float zpv = zp32[(size_t)t * CD + i];
        zq[i] = zpv + (emb[(size_t)k * CD + i] - zpv);
    }
    __syncthreads();
    for (int d = tid; d < DOUT; d += 256) {
        const float* w = Wp + (size_t)d * CD;
        float acc = 0.f;
        for (int c = 0; c < CD; ++c) acc += zq[c] * w[c];
        out[(size_t)t * DOUT + d] = acc + bp[d];
    }
}

__global__ __launch_bounds__(256) void k_loss1(const float* __restrict__ zp32,
                                               const float* __restrict__ emb,
                                               const int* __restrict__ idx,
                                               double* __restrict__ part,
                                               long long total, int CD) {
    double acc = 0.0;
    const long long stride = (long long)gridDim.x * 256;
    for (long long e = (long long)blockIdx.x * 256 + threadIdx.x; e < total; e += stride) {
        const long long t = e / CD;
        const int c = (int)(e - t * CD);
        const float df = emb[(size_t)idx[t] * CD + c] - zp32[e];
        acc += (double)df * (double)df;
    }
    __shared__ double red[256];
    red[threadIdx.x] = acc;
    __syncthreads();
    for (int s = 128; s > 0; s >>= 1) {
        if (threadIdx.x < s) red[threadIdx.x] += red[threadIdx.x + s];
        __syncthreads();
    }
    if (threadIdx.x == 0) part[blockIdx.x] = red[0];
}

__global__ __launch_bounds__(256) void k_loss2(const double* __restrict__ part,
                                               float* __restrict__ out_loss,
                                               double denom, int n) {
    __shared__ double red[256];
    const int tid = threadIdx.x;
    red[tid] = (tid < n) ? part[tid] : 0.0;
    __syncthreads();
    for (int s = 128; s > 0; s >>= 1) {
        if (tid < s) red[tid] += red[tid + s];
        __syncthreads();
    }
    if (tid == 0) *out_loss = (float)(1.25 * red[0] / denom);
}

extern "C" void kernel_launch(void* const* d_in, const int* in_sizes, int n_in,
                              void* d_out, int out_size, void* d_ws, size_t ws_size,
                              hipStream_t stream) {
    const float* z   = (const float*)d_in[0];
    const float* Wq  = (const float*)d_in[1];
    const float* bq  = (const float*)d_in[2];
    const float* emb = (const float*)d_in[3];
    const float* Wp  = (const float*)d_in[4];
    const float* bp  = (const float*)d_in[5];

    const int CD   = in_sizes[2];
    const int DIN  = in_sizes[1] / CD;
    const int DOUT = in_sizes[5];
    const int K    = in_sizes[3] / CD;
    const long long T = (long long)in_sizes[0] / DIN;

    float* out      = (float*)d_out;
    float* out_idx  = out + (size_t)T * DOUT;
    float* out_loss = out_idx + T;

    char* ws = (char*)d_ws;
    size_t off = 0;
    auto carve = [&](size_t bytes) -> char* {
        char* p = ws + off;
        off = (off + bytes + 255) & ~(size_t)255;
        return p;
    };
    float*  zp32  = (float*)carve((size_t)T * CD * 4);
    float*  A32   = (float*)carve((size_t)T * 4);
    float*  B32   = (float*)carve((size_t)K * 4);
    int*    idx   = (int*)carve((size_t)T * 4);
    double* part  = (double*)carve(128 * 8);
    double* ploss = (double*)carve((size_t)T * 8);

    // fast path: merged prep + 1 MFMA scan (ctile+slice maxima) + refine + out
    bool fast = (CD == 64) && (DIN == 256) && (K % 2048 == 0) && (K <= 16384) &&
                (T % 512 == 0);
    short8v* zpf = nullptr; short8v* ef = nullptr;
    float* bfl = nullptr; float* pmax32 = nullptr; float* pslice_t = nullptr;
    float4* embT4 = nullptr;
    const int NSLICE = 64;
    const int CT = K / 32;
    if (fast) {
        const int ztiles = (int)(T / 32);
        const int ctiles = CT;
        zpf      = (short8v*)carve((size_t)ztiles * 256 * 16);
        ef       = (short8v*)carve((size_t)ctiles * 256 * 16);
        bfl      = (float*)carve((size_t)ctiles * 32 * 4);
        pmax32   = (float*)carve((size_t)CT * T * 4);
        pslice_t = (float*)carve((size_t)T * NSLICE * 4);
        embT4    = (float4*)carve((size_t)K * 64 * 4);
        if (off > ws_size) fast = false;
    }

    if (fast) {
        const int tokblocks  = (int)(T / 32);
        const int codeblocks = K / 64;
        k_prep<<<dim3((unsigned)(tokblocks + codeblocks)), dim3(512), 0, stream>>>(
            z, Wq, bq, emb, zp32, A32, zpf, B32, ef, bfl, embT4, tokblocks, K);

        dim3 grid((unsigned)(T / 512), NSLICE);
        k_scan_max<<<grid, dim3(256), 0, stream>>>(zpf, ef, bfl, pmax32, pslice_t,
                                                   (int)T, K);

        k_refine_ct<<<dim3((unsigned)(T / 8)), dim3(256), 0, stream>>>(
            embT4, emb, zp32, A32, B32, pslice_t, pmax32, (int)T, CT, K,
            idx, out_idx, ploss);

        if (DOUT == 256 && T % 8 == 0) {
            k_out_v2<<<dim3((unsigned)(T / 8)), dim3(256), 0, stream>>>(
                emb, zp32, idx, Wp, bp, out, ploss, out_loss, (int)T, K,
                (double)T * CD, 1);
        } else {
            k_loss_red<<<dim3(1), dim3(256), 0, stream>>>(ploss, out_loss, (int)T,
                                                          (double)T * CD);
            k_out<<<dim3((unsigned)T), dim3(256), (size_t)CD * 4, stream>>>(
                emb, zp32, idx, Wp, bp, out, DOUT, CD);
        }
    } else {
        k_zp_np<<<dim3((unsigned)T), dim3(64), (size_t)DIN * 4, stream>>>(z, Wq, bq, zp32, DIN, CD);
        if (CD == 64)
            k_rowsum2_np<<<dim3((unsigned)((T + 255) / 256)), dim3(256), 0, stream>>>(zp32, A32, (int)T);
        else
            k_rowsum2_gen<<<dim3((unsigned)((T + 255) / 256)), dim3(256), 0, stream>>>(zp32, A32, (int)T, CD);
        if (CD == 64)
            k_rowsum2_np<<<dim3((K + 255) / 256), dim3(256), 0, stream>>>(emb, B32, K);
        else
            k_rowsum2_gen<<<dim3((K + 255) / 256), dim3(256), 0, stream>>>(emb, B32, K, CD);

        const size_t sm = (size_t)CD * 4 + 256 * 4 + 256 * 4;
        k_scan_gen<<<dim3((unsigned)T), dim3(256), sm, stream>>>(
            emb, zp32, A32, B32, idx, out_idx, K, CD);
        k_loss1<<<dim3(128), dim3(256), 0, stream>>>(zp32, emb, idx, part, (long long)T * CD, CD);
        k_loss2<<<dim3(1), dim3(256), 0, stream>>>(part, out_loss, (double)T * CD, 128);

        k_out<<<dim3((unsigned)T), dim3(256), (size_t)CD * 4, stream>>>(
            emb, zp32, idx, Wp, bp, out, DOUT, CD);
    }
}